// Round 1
// baseline (5354.938 us; speedup 1.0000x reference)
//
#include <hip/hip_runtime.h>

#define T_STEPS 256
#define BATCH   256
#define DIN     1024
#define DH      1024
#define KTOT    (DIN + DH)   // 2048

typedef _Float16 half8_t __attribute__((ext_vector_type(8)));
typedef float    f32x4_t __attribute__((ext_vector_type(4)));

// ---------------------------------------------------------------------------
// Convert W (1024 x 2048 fp32, row n, k contiguous) -> fp16 in workspace.
// 2,097,152 elements; 8 per thread; grid 1024 x 256.
// ---------------------------------------------------------------------------
__global__ __launch_bounds__(256) void cvt_w(const float* __restrict__ W,
                                             _Float16* __restrict__ Wh) {
    size_t base = ((size_t)blockIdx.x * 256 + threadIdx.x) * 8;
    const float4* s = reinterpret_cast<const float4*>(W + base);
    float4 a = s[0], b = s[1];
    half8_t h;
    h[0] = (_Float16)a.x; h[1] = (_Float16)a.y;
    h[2] = (_Float16)a.z; h[3] = (_Float16)a.w;
    h[4] = (_Float16)b.x; h[5] = (_Float16)b.y;
    h[6] = (_Float16)b.z; h[7] = (_Float16)b.w;
    *reinterpret_cast<half8_t*>(Wh + base) = h;
}

// ---------------------------------------------------------------------------
// out[0] = h0 = zeros (256 x 1024 fp32). 256 blocks x 256 thr x float4.
// ---------------------------------------------------------------------------
__global__ __launch_bounds__(256) void zero_h0(float* __restrict__ out) {
    size_t i = (size_t)blockIdx.x * 256 + threadIdx.x;
    reinterpret_cast<float4*>(out)[i] = make_float4(0.f, 0.f, 0.f, 0.f);
}

// ---------------------------------------------------------------------------
// One RNN step: O = tanh([H | X] @ W^T + b), M=256 K=2048 N=1024.
// Tile: BM=32 rows x BN=64 cols x BK=128. Grid (DH/64=16, BATCH/32=8) = 128 WGs.
// 256 threads = 4 waves in 2x2; each wave: 16x32 (two 16x16x32 f16 MFMA accs).
// LDS rows padded to 136 halves (+4 banks/row -> <=2-way conflict = free).
// ---------------------------------------------------------------------------
__global__ __launch_bounds__(256) void rnn_step(const float* __restrict__ seq,
                                                const _Float16* __restrict__ Wh,
                                                const float* __restrict__ bias,
                                                float* __restrict__ out,
                                                int t) {
    __shared__ _Float16 lds_a[32 * 136];
    __shared__ _Float16 lds_b[64 * 136];

    const int tid  = threadIdx.x;
    const int nblk = blockIdx.x;   // 0..15 (64 cols each)
    const int mblk = blockIdx.y;   // 0..7  (32 rows each)

    const float* __restrict__ H = out + (size_t)t * (BATCH * DH);
    const float* __restrict__ X = seq + (size_t)t * (BATCH * DIN);
    float* __restrict__ O       = out + (size_t)(t + 1) * (BATCH * DH);

    // A staging: 32 rows x 128 k fp32 -> fp16; 16 floats/thread.
    const int ar   = tid >> 3;           // 0..31
    const int ac   = (tid & 7) * 16;     // 0..112
    const int arow = mblk * 32 + ar;

    // B staging: 64 rows x 128 k fp16; 32 halves/thread.
    const int br   = tid >> 2;           // 0..63
    const int bc   = (tid & 3) * 32;     // 0..96
    const int brow = nblk * 64 + br;

    float4 a0, a1, a2, a3;
    uint4  bp0, bp1, bp2, bp3;

    auto load_a = [&](int kb) {
        const int k = kb + ac;           // whole BK tile is on one side of 1024
        const float* src = (k < DH) ? (H + (size_t)arow * DH + k)
                                    : (X + (size_t)arow * DIN + (k - DH));
        const float4* s4 = reinterpret_cast<const float4*>(src);
        a0 = s4[0]; a1 = s4[1]; a2 = s4[2]; a3 = s4[3];
    };
    auto store_a = [&]() {
        half8_t h0, h1;
        h0[0] = (_Float16)a0.x; h0[1] = (_Float16)a0.y;
        h0[2] = (_Float16)a0.z; h0[3] = (_Float16)a0.w;
        h0[4] = (_Float16)a1.x; h0[5] = (_Float16)a1.y;
        h0[6] = (_Float16)a1.z; h0[7] = (_Float16)a1.w;
        h1[0] = (_Float16)a2.x; h1[1] = (_Float16)a2.y;
        h1[2] = (_Float16)a2.z; h1[3] = (_Float16)a2.w;
        h1[4] = (_Float16)a3.x; h1[5] = (_Float16)a3.y;
        h1[6] = (_Float16)a3.z; h1[7] = (_Float16)a3.w;
        *reinterpret_cast<half8_t*>(&lds_a[ar * 136 + ac])     = h0;
        *reinterpret_cast<half8_t*>(&lds_a[ar * 136 + ac + 8]) = h1;
    };
    auto load_b = [&](int kb) {
        const uint4* s = reinterpret_cast<const uint4*>(Wh + (size_t)brow * KTOT + kb + bc);
        bp0 = s[0]; bp1 = s[1]; bp2 = s[2]; bp3 = s[3];
    };
    auto store_b = [&]() {
        uint4* d = reinterpret_cast<uint4*>(&lds_b[br * 136 + bc]);
        d[0] = bp0; d[1] = bp1; d[2] = bp2; d[3] = bp3;
    };

    const int wave = tid >> 6;
    const int lane = tid & 63;
    const int fr   = lane & 15;          // frag row (m for A, n for B, col for C)
    const int quad = lane >> 4;          // 0..3
    const int m0   = (wave >> 1) * 16;   // 0 / 16
    const int n0   = (wave & 1) * 32;    // 0 / 32

    f32x4_t acc0 = {0.f, 0.f, 0.f, 0.f};
    f32x4_t acc1 = {0.f, 0.f, 0.f, 0.f};

    load_a(0);
    load_b(0);

#pragma unroll 1
    for (int it = 0; it < KTOT / 128; ++it) {
        store_a();
        store_b();
        __syncthreads();
        if (it < KTOT / 128 - 1) {       // prefetch next K-tile into registers
            load_a((it + 1) * 128);
            load_b((it + 1) * 128);
        }
        const _Float16* pa  = &lds_a[(m0 + fr) * 136 + quad * 8];
        const _Float16* pb0 = &lds_b[(n0 + fr) * 136 + quad * 8];
        const _Float16* pb1 = &lds_b[(n0 + 16 + fr) * 136 + quad * 8];
#pragma unroll
        for (int kk = 0; kk < 4; ++kk) {
            half8_t af  = *reinterpret_cast<const half8_t*>(pa  + kk * 32);
            half8_t bf0 = *reinterpret_cast<const half8_t*>(pb0 + kk * 32);
            half8_t bf1 = *reinterpret_cast<const half8_t*>(pb1 + kk * 32);
            acc0 = __builtin_amdgcn_mfma_f32_16x16x32_f16(af, bf0, acc0, 0, 0, 0);
            acc1 = __builtin_amdgcn_mfma_f32_16x16x32_f16(af, bf1, acc1, 0, 0, 0);
        }
        __syncthreads();
    }

    // Epilogue: C/D layout col = lane&15, row = quad*4 + reg.
    const int   ng0 = nblk * 64 + n0 + fr;
    const int   ng1 = ng0 + 16;
    const float bv0 = bias[ng0];
    const float bv1 = bias[ng1];
    const int   mgb = mblk * 32 + m0 + quad * 4;
#pragma unroll
    for (int r = 0; r < 4; ++r) {
        O[(size_t)(mgb + r) * DH + ng0] = tanhf(acc0[r] + bv0);
        O[(size_t)(mgb + r) * DH + ng1] = tanhf(acc1[r] + bv1);
    }
}

// ---------------------------------------------------------------------------
extern "C" void kernel_launch(void* const* d_in, const int* in_sizes, int n_in,
                              void* d_out, int out_size, void* d_ws, size_t ws_size,
                              hipStream_t stream) {
    const float* seq  = (const float*)d_in[0];   // (256, 256, 1024) fp32
    const float* W    = (const float*)d_in[1];   // (1024, 2048) fp32
    const float* bias = (const float*)d_in[2];   // (1024,) fp32
    float* out        = (float*)d_out;           // (257, 256, 1024) fp32
    _Float16* Wh      = (_Float16*)d_ws;         // 4 MB fp16 W copy

    hipLaunchKernelGGL(cvt_w, dim3((DH * KTOT) / (256 * 8)), dim3(256), 0, stream, W, Wh);
    hipLaunchKernelGGL(zero_h0, dim3(256), dim3(256), 0, stream, out);
    for (int t = 0; t < T_STEPS; ++t) {
        hipLaunchKernelGGL(rnn_step, dim3(DH / 64, BATCH / 32), dim3(256), 0, stream,
                           seq, Wh, bias, out, t);
    }
}

// Round 2
// 3815.780 us; speedup vs baseline: 1.4034x; 1.4034x over previous
//
#include <hip/hip_runtime.h>

#define T_STEPS 256
#define BATCH   256
#define DIN     1024
#define DH      1024

typedef _Float16 half8_t __attribute__((ext_vector_type(8)));
typedef float    f32x4_t __attribute__((ext_vector_type(4)));

// ---------------------------------------------------------------------------
// Split W (1024 x 2048 fp32) into Wh = W[:, :1024] and Wx = W[:, 1024:], fp16.
// Blocks 0..511 -> Wh, 512..1023 -> Wx. 8 elements/thread.
// ---------------------------------------------------------------------------
__global__ __launch_bounds__(256) void cvt_w(const float* __restrict__ W,
                                             _Float16* __restrict__ Wh,
                                             _Float16* __restrict__ Wx) {
    const int part = blockIdx.x >> 9;                         // 0: Wh, 1: Wx
    size_t base = ((size_t)(blockIdx.x & 511) * 256 + threadIdx.x) * 8;
    const int n = (int)(base >> 10);
    const int k = (int)(base & 1023);
    const float4* s = reinterpret_cast<const float4*>(W + (size_t)n * 2048 + part * 1024 + k);
    float4 a = s[0], b = s[1];
    half8_t h;
    h[0] = (_Float16)a.x; h[1] = (_Float16)a.y;
    h[2] = (_Float16)a.z; h[3] = (_Float16)a.w;
    h[4] = (_Float16)b.x; h[5] = (_Float16)b.y;
    h[6] = (_Float16)b.z; h[7] = (_Float16)b.w;
    _Float16* dst = part ? Wx : Wh;
    *reinterpret_cast<half8_t*>(dst + base) = h;
}

// ---------------------------------------------------------------------------
// out[0] = h0 = zeros (256 x 1024 fp32).
// ---------------------------------------------------------------------------
__global__ __launch_bounds__(256) void zero_h0(float* __restrict__ out) {
    size_t i = (size_t)blockIdx.x * 256 + threadIdx.x;
    reinterpret_cast<float4*>(out)[i] = make_float4(0.f, 0.f, 0.f, 0.f);
}

// ---------------------------------------------------------------------------
// Z = seq @ Wx^T + bias, written into out[1..256].
// M = 65536, N = 1024, K = 1024. Tile 64x64, BK=128, 256 thr = 4 waves (2x2),
// each wave 32x32 = 2x2 accs of 16x16x32 f16 MFMA.
// Grid (16, 1024): x = nblk (fast) so co-resident WGs share the A m-stripe
// via L2/L3; Wx (2 MB) stays L2-resident.
// ---------------------------------------------------------------------------
__global__ __launch_bounds__(256) void zgemm(const float* __restrict__ seq,
                                             const _Float16* __restrict__ Wx,
                                             const float* __restrict__ bias,
                                             float* __restrict__ out) {
    __shared__ _Float16 la[64 * 136];
    __shared__ _Float16 lb[64 * 136];

    const int tid  = threadIdx.x;
    const int nblk = blockIdx.x;   // 0..15
    const int mblk = blockIdx.y;   // 0..1023

    const float* __restrict__ X = seq + (size_t)mblk * 64 * 1024;
    float* __restrict__ Z = out + (size_t)BATCH * DH + (size_t)mblk * 64 * 1024;

    // A: 64 rows x 128 k fp32 -> fp16. 32 floats (8 float4) per thread.
    const int ar = tid >> 2;            // 0..63
    const int ac = (tid & 3) * 32;      // 0..96
    // B: 64 rows x 128 k fp16. 32 halves (4 uint4) per thread.
    const int br = tid >> 2;
    const int bc = (tid & 3) * 32;
    const _Float16* Bsrc = Wx + (size_t)(nblk * 64 + br) * 1024;

    float4 af[8];
    uint4  bp[4];

    auto load_tiles = [&](int kb) {
        const float4* s4 = reinterpret_cast<const float4*>(X + (size_t)ar * 1024 + kb + ac);
#pragma unroll
        for (int i = 0; i < 8; ++i) af[i] = s4[i];
        const uint4* sb = reinterpret_cast<const uint4*>(Bsrc + kb + bc);
#pragma unroll
        for (int i = 0; i < 4; ++i) bp[i] = sb[i];
    };
    auto store_tiles = [&]() {
#pragma unroll
        for (int i = 0; i < 4; ++i) {
            half8_t h;
            h[0] = (_Float16)af[2 * i].x; h[1] = (_Float16)af[2 * i].y;
            h[2] = (_Float16)af[2 * i].z; h[3] = (_Float16)af[2 * i].w;
            h[4] = (_Float16)af[2 * i + 1].x; h[5] = (_Float16)af[2 * i + 1].y;
            h[6] = (_Float16)af[2 * i + 1].z; h[7] = (_Float16)af[2 * i + 1].w;
            *reinterpret_cast<half8_t*>(&la[ar * 136 + ac + 8 * i]) = h;
        }
        uint4* d = reinterpret_cast<uint4*>(&lb[br * 136 + bc]);
#pragma unroll
        for (int i = 0; i < 4; ++i) d[i] = bp[i];
    };

    const int wave = tid >> 6;
    const int lane = tid & 63;
    const int fr   = lane & 15;
    const int quad = lane >> 4;
    const int wm   = (wave >> 1) * 32;
    const int wn   = (wave & 1) * 32;

    f32x4_t acc[2][2] = {{{0.f,0.f,0.f,0.f},{0.f,0.f,0.f,0.f}},
                         {{0.f,0.f,0.f,0.f},{0.f,0.f,0.f,0.f}}};

    load_tiles(0);
#pragma unroll 1
    for (int it = 0; it < 8; ++it) {
        store_tiles();
        __syncthreads();
        if (it < 7) load_tiles((it + 1) * 128);
        const _Float16* pa0 = &la[(wm + fr) * 136 + quad * 8];
        const _Float16* pa1 = &la[(wm + 16 + fr) * 136 + quad * 8];
        const _Float16* pb0 = &lb[(wn + fr) * 136 + quad * 8];
        const _Float16* pb1 = &lb[(wn + 16 + fr) * 136 + quad * 8];
#pragma unroll
        for (int kk = 0; kk < 4; ++kk) {
            half8_t a0 = *reinterpret_cast<const half8_t*>(pa0 + kk * 32);
            half8_t a1 = *reinterpret_cast<const half8_t*>(pa1 + kk * 32);
            half8_t b0 = *reinterpret_cast<const half8_t*>(pb0 + kk * 32);
            half8_t b1 = *reinterpret_cast<const half8_t*>(pb1 + kk * 32);
            acc[0][0] = __builtin_amdgcn_mfma_f32_16x16x32_f16(a0, b0, acc[0][0], 0, 0, 0);
            acc[0][1] = __builtin_amdgcn_mfma_f32_16x16x32_f16(a0, b1, acc[0][1], 0, 0, 0);
            acc[1][0] = __builtin_amdgcn_mfma_f32_16x16x32_f16(a1, b0, acc[1][0], 0, 0, 0);
            acc[1][1] = __builtin_amdgcn_mfma_f32_16x16x32_f16(a1, b1, acc[1][1], 0, 0, 0);
        }
        __syncthreads();
    }

    // Epilogue: C/D layout col = lane&15, row = quad*4 + r. Add bias, write fp32.
    const float bv0 = bias[nblk * 64 + wn + fr];
    const float bv1 = bias[nblk * 64 + wn + 16 + fr];
#pragma unroll
    for (int i = 0; i < 2; ++i) {
        const int ml = wm + i * 16 + quad * 4;
#pragma unroll
        for (int r = 0; r < 4; ++r) {
            Z[(size_t)(ml + r) * 1024 + nblk * 64 + wn + fr]      = acc[i][0][r] + bv0;
            Z[(size_t)(ml + r) * 1024 + nblk * 64 + wn + 16 + fr] = acc[i][1][r] + bv1;
        }
    }
}

// ---------------------------------------------------------------------------
// One step: out[t+1] = tanh(out[t] @ Wh^T + out[t+1]), where out[t+1] holds
// Z_t + b from zgemm. M=256, N=1024, K=1024. Tile 32x32, grid (32, 8) = 256
// WGs (full CU coverage). 4 waves (2x2), each one 16x16 acc. BK=128.
// ---------------------------------------------------------------------------
__global__ __launch_bounds__(256) void rnn_step(const _Float16* __restrict__ Wh,
                                                float* __restrict__ out,
                                                int t) {
    __shared__ _Float16 la[32 * 136];
    __shared__ _Float16 lb[32 * 136];

    const int tid  = threadIdx.x;
    const int nblk = blockIdx.x;   // 0..31
    const int mblk = blockIdx.y;   // 0..7

    const float* __restrict__ H = out + (size_t)t * (BATCH * DH);
    float* __restrict__ O       = out + (size_t)(t + 1) * (BATCH * DH);

    // A: 32 rows x 128 k fp32 -> fp16; 16 floats (4 float4)/thread.
    const int ar = tid >> 3;            // 0..31
    const int ac = (tid & 7) * 16;      // 0..112
    const float* Asrc = H + (size_t)(mblk * 32 + ar) * 1024;
    // B: 32 rows x 128 k fp16; 16 halves (2 uint4)/thread.
    const int br = tid >> 3;
    const int bc = (tid & 7) * 16;
    const _Float16* Bsrc = Wh + (size_t)(nblk * 32 + br) * 1024;

    float4 a0, a1, a2, a3;
    uint4  bp0, bp1;

    auto load_tiles = [&](int kb) {
        const float4* s4 = reinterpret_cast<const float4*>(Asrc + kb + ac);
        a0 = s4[0]; a1 = s4[1]; a2 = s4[2]; a3 = s4[3];
        const uint4* sb = reinterpret_cast<const uint4*>(Bsrc + kb + bc);
        bp0 = sb[0]; bp1 = sb[1];
    };
    auto store_tiles = [&]() {
        half8_t h0, h1;
        h0[0] = (_Float16)a0.x; h0[1] = (_Float16)a0.y;
        h0[2] = (_Float16)a0.z; h0[3] = (_Float16)a0.w;
        h0[4] = (_Float16)a1.x; h0[5] = (_Float16)a1.y;
        h0[6] = (_Float16)a1.z; h0[7] = (_Float16)a1.w;
        h1[0] = (_Float16)a2.x; h1[1] = (_Float16)a2.y;
        h1[2] = (_Float16)a2.z; h1[3] = (_Float16)a2.w;
        h1[4] = (_Float16)a3.x; h1[5] = (_Float16)a3.y;
        h1[6] = (_Float16)a3.z; h1[7] = (_Float16)a3.w;
        *reinterpret_cast<half8_t*>(&la[ar * 136 + ac])     = h0;
        *reinterpret_cast<half8_t*>(&la[ar * 136 + ac + 8]) = h1;
        uint4* d = reinterpret_cast<uint4*>(&lb[br * 136 + bc]);
        d[0] = bp0; d[1] = bp1;
    };

    const int wave = tid >> 6;
    const int lane = tid & 63;
    const int fr   = lane & 15;
    const int quad = lane >> 4;
    const int m0   = (wave >> 1) * 16;
    const int n0   = (wave & 1) * 16;

    f32x4_t acc = {0.f, 0.f, 0.f, 0.f};

    load_tiles(0);
#pragma unroll 1
    for (int it = 0; it < 8; ++it) {
        store_tiles();
        __syncthreads();
        if (it < 7) load_tiles((it + 1) * 128);
        const _Float16* pa = &la[(m0 + fr) * 136 + quad * 8];
        const _Float16* pb = &lb[(n0 + fr) * 136 + quad * 8];
#pragma unroll
        for (int kk = 0; kk < 4; ++kk) {
            half8_t a = *reinterpret_cast<const half8_t*>(pa + kk * 32);
            half8_t b = *reinterpret_cast<const half8_t*>(pb + kk * 32);
            acc = __builtin_amdgcn_mfma_f32_16x16x32_f16(a, b, acc, 0, 0, 0);
        }
        __syncthreads();
    }

    // Epilogue: fuse Z (already in O) and tanh.
    const int ng = nblk * 32 + n0 + fr;
    const int mg = mblk * 32 + m0 + quad * 4;
#pragma unroll
    for (int r = 0; r < 4; ++r) {
        const size_t idx = (size_t)(mg + r) * DH + ng;
        O[idx] = tanhf(acc[r] + O[idx]);
    }
}

// ---------------------------------------------------------------------------
extern "C" void kernel_launch(void* const* d_in, const int* in_sizes, int n_in,
                              void* d_out, int out_size, void* d_ws, size_t ws_size,
                              hipStream_t stream) {
    const float* seq  = (const float*)d_in[0];   // (256, 256, 1024) fp32
    const float* W    = (const float*)d_in[1];   // (1024, 2048) fp32
    const float* bias = (const float*)d_in[2];   // (1024,) fp32
    float* out        = (float*)d_out;           // (257, 256, 1024) fp32
    _Float16* Wh      = (_Float16*)d_ws;                 // 2 MB
    _Float16* Wx      = (_Float16*)d_ws + 1024 * 1024;   // 2 MB

    hipLaunchKernelGGL(cvt_w, dim3(1024), dim3(256), 0, stream, W, Wh, Wx);
    hipLaunchKernelGGL(zero_h0, dim3(256), dim3(256), 0, stream, out);
    hipLaunchKernelGGL(zgemm, dim3(16, 1024), dim3(256), 0, stream, seq, Wx, bias, out);
    for (int t = 0; t < T_STEPS; ++t) {
        hipLaunchKernelGGL(rnn_step, dim3(32, 8), dim3(256), 0, stream, Wh, out, t);
    }
}